// Round 3
// baseline (518.377 us; speedup 1.0000x reference)
//
#include <hip/hip_runtime.h>
#include <cmath>

typedef __bf16 bf16;
typedef __bf16 bf16x8 __attribute__((ext_vector_type(8)));
typedef __bf16 bf16x4 __attribute__((ext_vector_type(4)));
typedef float  f32x4  __attribute__((ext_vector_type(4)));
typedef unsigned int u32x4 __attribute__((ext_vector_type(4)));

#define MFMA16(a, b, c) __builtin_amdgcn_mfma_f32_16x16x32_bf16((a), (b), (c), 0, 0, 0)
#define LOG2E 1.44269504088896f

static __device__ __forceinline__ void gl_lds16(const void* g, void* l) {
    __builtin_amdgcn_global_load_lds((const __attribute__((address_space(1))) void*)g,
                                     (__attribute__((address_space(3))) void*)l, 16, 0, 0);
}

static __device__ __forceinline__ bf16x8 bneg8(bf16x8 x) {
    u32x4 u = __builtin_bit_cast(u32x4, x);
    u = u ^ 0x80008000u;
    return __builtin_bit_cast(bf16x8, u);
}

static __device__ __forceinline__ f32x4 zero4() {
    return f32x4{0.0f, 0.0f, 0.0f, 0.0f};
}

// ---------------------------------------------------------------------------
// small utility kernels
// ---------------------------------------------------------------------------
__global__ void fill_kernel(float* p, float v, int n) {
    for (int i = blockIdx.x * blockDim.x + threadIdx.x; i < n; i += gridDim.x * blockDim.x)
        p[i] = v;
}

// fused 8-way f32 -> bf16 weight conversion (all sizes % 1024 == 0)
struct Cvt8 {
    const float* s[8];
    bf16* d[8];
    int boff[9];  // cumulative block offsets
};
__global__ __launch_bounds__(256) void cvt8_kernel(Cvt8 c) {
    int blk = blockIdx.x;
    int seg = 0;
#pragma unroll
    for (int k = 0; k < 7; ++k)
        if (blk >= c.boff[k + 1]) seg = k + 1;
    const int local = blk - c.boff[seg];
    const int i = local * 1024 + threadIdx.x * 4;
    const float4 v = *(const float4*)(c.s[seg] + i);
    bf16x4 o;
    o[0] = (bf16)v.x; o[1] = (bf16)v.y; o[2] = (bf16)v.z; o[3] = (bf16)v.w;
    *(bf16x4*)(c.d[seg] + i) = o;
}

// ---------------------------------------------------------------------------
// complex magnitude layernorm. ILV=true: xa is interleaved float2 [row][768][2]
// ---------------------------------------------------------------------------
template <bool ILV>
__global__ __launch_bounds__(256) void cln_kernel(
    const float* __restrict__ xa, const float* __restrict__ xb,
    const float* __restrict__ gamma, const float* __restrict__ beta,
    bf16* __restrict__ nr, bf16* __restrict__ ni) {
    __shared__ float red[4];
    const int t = threadIdx.x;
    const size_t base = (size_t)blockIdx.x * 768;

    float r[3], im[3], mg[3];
#pragma unroll
    for (int j = 0; j < 3; ++j) {
        const int f = t + j * 256;
        if (ILV) {
            const float2 v = ((const float2*)xa)[base + f];
            r[j] = v.x;
            im[j] = v.y;
        } else {
            r[j] = xa[base + f];
            im[j] = xb[base + f];
        }
        mg[j] = __builtin_amdgcn_sqrtf(r[j] * r[j] + im[j] * im[j] + 1e-6f);
    }
    float s = mg[0] + mg[1] + mg[2];
#pragma unroll
    for (int m = 32; m >= 1; m >>= 1) s += __shfl_xor(s, m);
    if ((t & 63) == 0) red[t >> 6] = s;
    __syncthreads();
    const float mean = (red[0] + red[1] + red[2] + red[3]) * (1.0f / 768.0f);
    __syncthreads();

    float v2 = 0.0f;
#pragma unroll
    for (int j = 0; j < 3; ++j) {
        const float d = mg[j] - mean;
        v2 += d * d;
    }
#pragma unroll
    for (int m = 32; m >= 1; m >>= 1) v2 += __shfl_xor(v2, m);
    if ((t & 63) == 0) red[t >> 6] = v2;
    __syncthreads();
    const float var = (red[0] + red[1] + red[2] + red[3]) * (1.0f / 768.0f);
    const float rstd = rsqrtf(var + 1e-6f);

#pragma unroll
    for (int j = 0; j < 3; ++j) {
        const int f = t + j * 256;
        const float sc = (mg[j] - mean) * rstd / (mg[j] + 1e-6f);
        nr[base + f] = (bf16)(gamma[2 * f] * (r[j] * sc) + beta[2 * f]);
        ni[base + f] = (bf16)(gamma[2 * f + 1] * (im[j] * sc) + beta[2 * f + 1]);
    }
}

// ---------------------------------------------------------------------------
// complex GEMM (NT) with global_load_lds staging + XCD-aware block swizzle
// MODE 1: resr is interleaved float2 residual (the original x)
// ---------------------------------------------------------------------------
template <int MODE>
__global__ __launch_bounds__(256, 2) void cgemm_kernel(
    const bf16* __restrict__ Ar, const bf16* __restrict__ Ai,
    const bf16* __restrict__ Wr, const bf16* __restrict__ Wi,
    const float* __restrict__ br, const float* __restrict__ bi,
    const float* __restrict__ resr, const float* __restrict__ resi,
    float* __restrict__ outFr, float* __restrict__ outFi,
    bf16* __restrict__ outBr, bf16* __restrict__ outBi,
    int N, int K) {
    __shared__ bf16 sAr[128][32];
    __shared__ bf16 sAi[128][32];
    __shared__ bf16 sBr[128][32];
    __shared__ bf16 sBi[128][32];

    const int tid = threadIdx.x;
    const int wave = tid >> 6, lane = tid & 63;
    const int lg = lane >> 4, lr = lane & 15;

    // XCD-aware swizzle (all grids have nwg % 8 == 0)
    const int nwgx = gridDim.x;
    int wg = blockIdx.y * nwgx + blockIdx.x;
    const int cpx = (nwgx * gridDim.y) >> 3;
    wg = (wg & 7) * cpx + (wg >> 3);
    const int row0 = (wg % nwgx) * 128, col0 = (wg / nwgx) * 128;

    const int wm = (wave >> 1) * 64, wn = (wave & 1) * 64;
    const int srow = lane >> 2;
    const int sc8 = (lane & 3) * 8;

    f32x4 accr[4][4], acci[4][4];
#pragma unroll
    for (int a = 0; a < 4; ++a)
#pragma unroll
        for (int b2 = 0; b2 < 4; ++b2) {
            accr[a][b2] = zero4();
            acci[a][b2] = zero4();
        }

    for (int kt = 0; kt < K; kt += 32) {
        __syncthreads();
#pragma unroll
        for (int s = 0; s < 2; ++s) {
            const int seg = wave * 2 + s;
            const int row = seg * 16 + srow;
            const size_t ga = (size_t)(row0 + row) * K + kt + sc8;
            const size_t gb = (size_t)(col0 + row) * K + kt + sc8;
            gl_lds16(Ar + ga, &sAr[seg * 16][0]);
            gl_lds16(Ai + ga, &sAi[seg * 16][0]);
            gl_lds16(Wr + gb, &sBr[seg * 16][0]);
            gl_lds16(Wi + gb, &sBi[seg * 16][0]);
        }
        __syncthreads();

        bf16x8 ar[4], ai[4], an[4];
#pragma unroll
        for (int mt = 0; mt < 4; ++mt) {
            ar[mt] = *(const bf16x8*)(&sAr[wm + mt * 16 + lr][lg * 8]);
            ai[mt] = *(const bf16x8*)(&sAi[wm + mt * 16 + lr][lg * 8]);
            an[mt] = bneg8(ai[mt]);
        }
#pragma unroll
        for (int nt = 0; nt < 4; ++nt) {
            const bf16x8 br8 = *(const bf16x8*)(&sBr[wn + nt * 16 + lr][lg * 8]);
            const bf16x8 bi8 = *(const bf16x8*)(&sBi[wn + nt * 16 + lr][lg * 8]);
#pragma unroll
            for (int mt = 0; mt < 4; ++mt) {
                accr[mt][nt] = MFMA16(ar[mt], br8, accr[mt][nt]);
                accr[mt][nt] = MFMA16(an[mt], bi8, accr[mt][nt]);
                acci[mt][nt] = MFMA16(ar[mt], bi8, acci[mt][nt]);
                acci[mt][nt] = MFMA16(ai[mt], br8, acci[mt][nt]);
            }
        }
    }

#pragma unroll
    for (int nt = 0; nt < 4; ++nt) {
        const int col = col0 + wn + nt * 16 + lr;
        const float bre = br[col], bie = bi[col];
#pragma unroll
        for (int mt = 0; mt < 4; ++mt) {
#pragma unroll
            for (int j = 0; j < 4; ++j) {
                const int row = row0 + wm + mt * 16 + lg * 4 + j;
                float vr = accr[mt][nt][j] + bre;
                float vi = acci[mt][nt][j] + bie;
                const size_t o = (size_t)row * N + col;
                if (MODE == 0) {
                    outBr[o] = (bf16)vr;
                    outBi[o] = (bf16)vi;
                } else if (MODE == 1) {
                    const float2 rv = ((const float2*)resr)[(size_t)row * 768 + col];
                    outFr[o] = rv.x + vr;
                    outFi[o] = rv.y + vi;
                } else if (MODE == 2) {
                    vr = 0.5f * vr * (1.0f + erff(vr * 0.70710678118654752f));
                    vi = 0.5f * vi * (1.0f + erff(vi * 0.70710678118654752f));
                    outBr[o] = (bf16)vr;
                    outBi[o] = (bf16)vi;
                } else {
                    const size_t ro = (size_t)row * 768 + col;
                    outFr[(size_t)row * 1536 + 2 * col]     = resr[ro] + vr;
                    outFr[(size_t)row * 1536 + 2 * col + 1] = resi[ro] + vi;
                }
            }
        }
    }
}

// ---------------------------------------------------------------------------
// transpose V slice of qkv into [B*nH][64 d][2048 n] bf16 planes
// ---------------------------------------------------------------------------
__global__ __launch_bounds__(256) void vtrans_kernel(
    const bf16* __restrict__ qkvr, const bf16* __restrict__ qkvi,
    bf16* __restrict__ vtr, bf16* __restrict__ vti) {
    __shared__ bf16 sr[64][65];
    __shared__ bf16 si[64][65];
    const int t = threadIdx.x;
    const int nb = blockIdx.x, h = blockIdx.y, b = blockIdx.z;
    const size_t ld = 2304;
    const bf16* srcr = qkvr + (size_t)(b * 2048 + nb * 64) * ld + 1536 + h * 64;
    const bf16* srci = qkvi + (size_t)(b * 2048 + nb * 64) * ld + 1536 + h * 64;
#pragma unroll
    for (int j = 0; j < 16; ++j) {
        const int idx = t + 256 * j;
        const int n = idx >> 6, d = idx & 63;
        sr[n][d] = srcr[(size_t)n * ld + d];
        si[n][d] = srci[(size_t)n * ld + d];
    }
    __syncthreads();
    bf16* dstr = vtr + (size_t)(b * 12 + h) * 64 * 2048 + nb * 64;
    bf16* dsti = vti + (size_t)(b * 12 + h) * 64 * 2048 + nb * 64;
#pragma unroll
    for (int j = 0; j < 16; ++j) {
        const int idx = t + 256 * j;
        const int d = idx >> 6, n = idx & 63;
        dstr[(size_t)d * 2048 + n] = sr[n][d];
        dsti[(size_t)d * 2048 + n] = si[n][d];
    }
}

// ---------------------------------------------------------------------------
// fused complex flash attention v3:
// 4 waves x 32 q-rows (block = 128 q), 64-key tiles,
// single-buffered K/V LDS with T14 async reg-staging (swizzled ds_write),
// per-wave P round-trip through small LDS tile.
// ---------------------------------------------------------------------------
__global__ __launch_bounds__(256, 2) void cattn_kernel(
    const bf16* __restrict__ qkvr, const bf16* __restrict__ qkvi,
    const bf16* __restrict__ vtr, const bf16* __restrict__ vti,
    bf16* __restrict__ aor, bf16* __restrict__ aoi) {
    __shared__ __align__(16) bf16 sK[2][64][64];  // [plane][key][d], chunk-swizzled
    __shared__ __align__(16) bf16 sV[2][64][64];  // [plane][d][key], chunk-swizzled
    __shared__ __align__(16) bf16 sP[4][16][72];  // per-wave P (reused per q-tile)

    const int tid = threadIdx.x;
    const int w = tid >> 6, lane = tid & 63;
    const int lg = lane >> 4, lr = lane & 15;
    const int qb = blockIdx.x, h = blockIdx.y, b = blockIdx.z;
    const int ld = 2304;
    const int kx = lr & 7;

    const bf16* kbase0 = qkvr + (size_t)b * 2048 * ld + 768 + h * 64;
    const bf16* kbase1 = qkvi + (size_t)b * 2048 * ld + 768 + h * 64;
    const bf16* vbase0 = vtr + (size_t)(b * 12 + h) * 64 * 2048;
    const bf16* vbase1 = vti + (size_t)(b * 12 + h) * 64 * 2048;

    // staging: 2048 16B-chunks total; cid = j*256 + tid
    // cid -> arr (K/V), plane, row (0..63), chunk c (0..7)
    float4 stg[8];
    auto issue = [&](int kt) {
#pragma unroll
        for (int j = 0; j < 8; ++j) {
            const int cid = j * 256 + tid;
            const int arr = cid >> 10, pl = (cid >> 9) & 1;
            const int row = (cid >> 3) & 63, c = cid & 7;
            const bf16* src;
            if (arr == 0)
                src = (pl ? kbase1 : kbase0) + (size_t)(kt * 64 + row) * ld + c * 8;
            else
                src = (pl ? vbase1 : vbase0) + (size_t)row * 2048 + kt * 64 + c * 8;
            stg[j] = *(const float4*)src;
        }
    };
    auto commit = [&]() {
#pragma unroll
        for (int j = 0; j < 8; ++j) {
            const int cid = j * 256 + tid;
            const int arr = cid >> 10, pl = (cid >> 9) & 1;
            const int row = (cid >> 3) & 63, c = cid & 7;
            const int slot = c ^ (row & 7);
            bf16* dst = arr == 0 ? &sK[pl][row][slot * 8] : &sV[pl][row][slot * 8];
            *(float4*)dst = stg[j];
        }
    };

    // Q fragments: 2 q-tiles of 16 rows per wave
    bf16x8 aqr[2][2], aqi[2][2];
#pragma unroll
    for (int qt = 0; qt < 2; ++qt) {
        const size_t qoff =
            (size_t)(b * 2048 + qb * 128 + w * 32 + qt * 16 + lr) * ld + h * 64;
#pragma unroll
        for (int ks = 0; ks < 2; ++ks) {
            aqr[qt][ks] = *(const bf16x8*)(qkvr + qoff + ks * 32 + lg * 8);
            aqi[qt][ks] = *(const bf16x8*)(qkvi + qoff + ks * 32 + lg * 8);
        }
    }

    f32x4 our[2][4], oui[2][4];
#pragma unroll
    for (int qt = 0; qt < 2; ++qt)
#pragma unroll
        for (int d = 0; d < 4; ++d) {
            our[qt][d] = zero4();
            oui[qt][d] = zero4();
        }
    float mrun[2] = {-1e30f, -1e30f}, lrun[2] = {0.0f, 0.0f};

    issue(0);
    commit();
    __syncthreads();

    for (int kt = 0; kt < 32; ++kt) {
        if (kt < 31) issue(kt + 1);  // async prefetch into regs

        // ---- QK^T with per-t magnitude (frees score regs early) ----
        float pq[2][16];
        float tmax[2] = {-1e30f, -1e30f};
#pragma unroll
        for (int t = 0; t < 4; ++t) {
            f32x4 str[2], sti[2];
#pragma unroll
            for (int qt = 0; qt < 2; ++qt) {
                str[qt] = zero4();
                sti[qt] = zero4();
            }
#pragma unroll
            for (int ks = 0; ks < 2; ++ks) {
                const int ch = (((ks << 2) | lg) ^ kx) << 3;
                const bf16x8 kr8 = *(const bf16x8*)(&sK[0][t * 16 + lr][ch]);
                const bf16x8 ki8 = *(const bf16x8*)(&sK[1][t * 16 + lr][ch]);
                const bf16x8 kn8 = bneg8(kr8);
#pragma unroll
                for (int qt = 0; qt < 2; ++qt) {
                    str[qt] = MFMA16(kr8, aqr[qt][ks], str[qt]);
                    str[qt] = MFMA16(ki8, aqi[qt][ks], str[qt]);
                    sti[qt] = MFMA16(ki8, aqr[qt][ks], sti[qt]);
                    sti[qt] = MFMA16(kn8, aqi[qt][ks], sti[qt]);
                }
            }
#pragma unroll
            for (int qt = 0; qt < 2; ++qt)
#pragma unroll
                for (int j = 0; j < 4; ++j) {
                    const float sr = str[qt][j], si = sti[qt][j];
                    const float m =
                        __builtin_amdgcn_sqrtf(sr * sr + si * si + 1e-8f) * 0.125f;
                    pq[qt][t * 4 + j] = m;
                    tmax[qt] = fmaxf(tmax[qt], m);
                }
        }

        // ---- softmax per q-tile, P -> LDS -> PV A-fragments ----
        bf16x8 pf[2][2];
#pragma unroll
        for (int qt = 0; qt < 2; ++qt) {
            float tm = tmax[qt];
            tm = fmaxf(tm, __shfl_xor(tm, 16));
            tm = fmaxf(tm, __shfl_xor(tm, 32));

            if (!__all(tm <= mrun[qt])) {
                const float mnew = fmaxf(mrun[qt], tm);
                const float corr = __builtin_amdgcn_exp2f((mrun[qt] - mnew) * LOG2E);
                float cj[4];
#pragma unroll
                for (int j = 0; j < 4; ++j) cj[j] = __shfl(corr, lg * 4 + j);
#pragma unroll
                for (int d = 0; d < 4; ++d)
#pragma unroll
                    for (int j = 0; j < 4; ++j) {
                        our[qt][d][j] *= cj[j];
                        oui[qt][d][j] *= cj[j];
                    }
                lrun[qt] *= corr;
                mrun[qt] = mnew;
            }

            float ls = 0.0f;
#pragma unroll
            for (int i = 0; i < 16; ++i) {
                pq[qt][i] = __builtin_amdgcn_exp2f((pq[qt][i] - mrun[qt]) * LOG2E);
                ls += pq[qt][i];
            }
            ls += __shfl_xor(ls, 16);
            ls += __shfl_xor(ls, 32);
            lrun[qt] += ls;

#pragma unroll
            for (int t = 0; t < 4; ++t) {
                bf16x4 pk;
#pragma unroll
                for (int j = 0; j < 4; ++j) pk[j] = (bf16)pq[qt][t * 4 + j];
                *(bf16x4*)(&sP[w][lr][t * 16 + lg * 4]) = pk;
            }
            pf[qt][0] = *(const bf16x8*)(&sP[w][lr][lg * 8]);
            pf[qt][1] = *(const bf16x8*)(&sP[w][lr][32 + lg * 8]);
        }

        // ---- PV: V fragments shared across both q-tiles ----
#pragma unroll
        for (int d = 0; d < 4; ++d) {
#pragma unroll
            for (int ks2 = 0; ks2 < 2; ++ks2) {
                const int ch = (((ks2 << 2) | lg) ^ kx) << 3;
                const bf16x8 vr8 = *(const bf16x8*)(&sV[0][d * 16 + lr][ch]);
                const bf16x8 vi8 = *(const bf16x8*)(&sV[1][d * 16 + lr][ch]);
#pragma unroll
                for (int qt = 0; qt < 2; ++qt) {
                    our[qt][d] = MFMA16(pf[qt][ks2], vr8, our[qt][d]);
                    oui[qt][d] = MFMA16(pf[qt][ks2], vi8, oui[qt][d]);
                }
            }
        }

        __syncthreads();               // all waves done reading K/V
        if (kt < 31) commit();         // swizzled ds_write of next tile
        __syncthreads();               // LDS ready
    }

#pragma unroll
    for (int qt = 0; qt < 2; ++qt) {
        float linv[4];
#pragma unroll
        for (int j = 0; j < 4; ++j) {
            const float lj = __shfl(lrun[qt], lg * 4 + j);
            linv[j] = __builtin_amdgcn_rcpf(lj);
        }
#pragma unroll
        for (int d = 0; d < 4; ++d)
#pragma unroll
            for (int j = 0; j < 4; ++j) {
                const int row = b * 2048 + qb * 128 + w * 32 + qt * 16 + lg * 4 + j;
                const int col = h * 64 + d * 16 + lr;
                aor[(size_t)row * 768 + col] = (bf16)(our[qt][d][j] * linv[j]);
                aoi[(size_t)row * 768 + col] = (bf16)(oui[qt][d][j] * linv[j]);
            }
    }
}

// ---------------------------------------------------------------------------
// host launch
// ---------------------------------------------------------------------------
extern "C" void kernel_launch(void* const* d_in, const int* in_sizes, int n_in,
                              void* d_out, int out_size, void* d_ws, size_t ws_size,
                              hipStream_t stream) {
    const float* x      = (const float*)d_in[0];
    const float* n1g    = (const float*)d_in[1];
    const float* n1b    = (const float*)d_in[2];
    const float* qkvwr  = (const float*)d_in[3];
    const float* qkvwi  = (const float*)d_in[4];
    const float* qkvbr  = (const float*)d_in[5];
    const float* qkvbi  = (const float*)d_in[6];
    const float* projwr = (const float*)d_in[7];
    const float* projwi = (const float*)d_in[8];
    const float* projbr = (const float*)d_in[9];
    const float* projbi = (const float*)d_in[10];
    const float* n2g    = (const float*)d_in[11];
    const float* n2b    = (const float*)d_in[12];
    const float* fc1wr  = (const float*)d_in[13];
    const float* fc1wi  = (const float*)d_in[14];
    const float* fc1br  = (const float*)d_in[15];
    const float* fc1bi  = (const float*)d_in[16];
    const float* fc2wr  = (const float*)d_in[17];
    const float* fc2wi  = (const float*)d_in[18];
    const float* fc2br  = (const float*)d_in[19];
    const float* fc2bi  = (const float*)d_in[20];

    const int M = 4096, E = 768, E3 = 2304, HH = 1536;

    char* base = (char*)d_ws;
    size_t off = 0;
    auto alloc = [&](size_t bytes) -> void* {
        void* p = base + off;
        off += (bytes + 255) & ~(size_t)255;
        return p;
    };
    float* xr2 = (float*)alloc((size_t)M * E * 4);
    float* xi2 = (float*)alloc((size_t)M * E * 4);
    bf16* nr   = (bf16*)alloc((size_t)M * E * 2);
    bf16* ni   = (bf16*)alloc((size_t)M * E * 2);
    bf16* wqr  = (bf16*)alloc((size_t)E3 * E * 2);
    bf16* wqi  = (bf16*)alloc((size_t)E3 * E * 2);
    bf16* wpr  = (bf16*)alloc((size_t)E * E * 2);
    bf16* wpi  = (bf16*)alloc((size_t)E * E * 2);
    bf16* w1r  = (bf16*)alloc((size_t)HH * E * 2);
    bf16* w1i  = (bf16*)alloc((size_t)HH * E * 2);
    bf16* w2r  = (bf16*)alloc((size_t)E * HH * 2);
    bf16* w2i  = (bf16*)alloc((size_t)E * HH * 2);
    bf16* qkr  = (bf16*)alloc((size_t)M * E3 * 2);
    bf16* qki  = (bf16*)alloc((size_t)M * E3 * 2);
    bf16* vtr  = (bf16*)alloc((size_t)24 * 64 * 2048 * 2);
    bf16* vti  = (bf16*)alloc((size_t)24 * 64 * 2048 * 2);
    bf16* aor  = (bf16*)alloc((size_t)M * E * 2);
    bf16* aoi  = (bf16*)alloc((size_t)M * E * 2);
    bf16* hr   = (bf16*)alloc((size_t)M * HH * 2);
    bf16* hi   = (bf16*)alloc((size_t)M * HH * 2);

    if (off > ws_size) {
        fill_kernel<<<1024, 256, 0, stream>>>((float*)d_out, 1.0e9f, out_size);
        return;
    }

    // fused weight conversion (block counts: n/1024 each)
    Cvt8 c;
    c.s[0] = qkvwr; c.d[0] = wqr;
    c.s[1] = qkvwi; c.d[1] = wqi;
    c.s[2] = projwr; c.d[2] = wpr;
    c.s[3] = projwi; c.d[3] = wpi;
    c.s[4] = fc1wr; c.d[4] = w1r;
    c.s[5] = fc1wi; c.d[5] = w1i;
    c.s[6] = fc2wr; c.d[6] = w2r;
    c.s[7] = fc2wi; c.d[7] = w2i;
    const int nseg[8] = {E3 * E, E3 * E, E * E, E * E, HH * E, HH * E, E * HH, E * HH};
    int cum = 0;
    for (int k = 0; k < 8; ++k) {
        c.boff[k] = cum;
        cum += nseg[k] / 1024;
    }
    c.boff[8] = cum;
    cvt8_kernel<<<cum, 256, 0, stream>>>(c);

    // LN1 (reads interleaved x directly)
    cln_kernel<true><<<M, 256, 0, stream>>>(x, nullptr, n1g, n1b, nr, ni);
    // QKV
    cgemm_kernel<0><<<dim3(32, 18), 256, 0, stream>>>(nr, ni, wqr, wqi, qkvbr, qkvbi,
                                                      nullptr, nullptr, nullptr, nullptr,
                                                      qkr, qki, E3, E);
    // V transpose
    vtrans_kernel<<<dim3(32, 12, 2), 256, 0, stream>>>(qkr, qki, vtr, vti);
    // attention (128 q-rows per block)
    cattn_kernel<<<dim3(16, 12, 2), 256, 0, stream>>>(qkr, qki, vtr, vti, aor, aoi);
    // proj + interleaved-x residual -> f32 planes
    cgemm_kernel<1><<<dim3(32, 6), 256, 0, stream>>>(aor, aoi, wpr, wpi, projbr, projbi,
                                                     x, nullptr, xr2, xi2, nullptr, nullptr,
                                                     E, E);
    // LN2
    cln_kernel<false><<<M, 256, 0, stream>>>(xr2, xi2, n2g, n2b, nr, ni);
    // FC1 + gelu
    cgemm_kernel<2><<<dim3(32, 12), 256, 0, stream>>>(nr, ni, w1r, w1i, fc1br, fc1bi,
                                                      nullptr, nullptr, nullptr, nullptr,
                                                      hr, hi, HH, E);
    // FC2 + residual -> interleaved d_out
    cgemm_kernel<3><<<dim3(32, 6), 256, 0, stream>>>(hr, hi, w2r, w2i, fc2br, fc2bi,
                                                     xr2, xi2, (float*)d_out, nullptr,
                                                     nullptr, nullptr, E, HH);
}

// Round 4
// 415.080 us; speedup vs baseline: 1.2489x; 1.2489x over previous
//
#include <hip/hip_runtime.h>
#include <cmath>

typedef __bf16 bf16;
typedef __bf16 bf16x8 __attribute__((ext_vector_type(8)));
typedef __bf16 bf16x4 __attribute__((ext_vector_type(4)));
typedef float  f32x4  __attribute__((ext_vector_type(4)));
typedef unsigned int u32x4 __attribute__((ext_vector_type(4)));

#define MFMA16(a, b, c) __builtin_amdgcn_mfma_f32_16x16x32_bf16((a), (b), (c), 0, 0, 0)
#define LOG2E 1.44269504088896f

static __device__ __forceinline__ void gl_lds16(const void* g, void* l) {
    __builtin_amdgcn_global_load_lds((const __attribute__((address_space(1))) void*)g,
                                     (__attribute__((address_space(3))) void*)l, 16, 0, 0);
}

static __device__ __forceinline__ bf16x8 bneg8(bf16x8 x) {
    u32x4 u = __builtin_bit_cast(u32x4, x);
    u = u ^ 0x80008000u;
    return __builtin_bit_cast(bf16x8, u);
}

static __device__ __forceinline__ f32x4 zero4() {
    return f32x4{0.0f, 0.0f, 0.0f, 0.0f};
}

// ---------------------------------------------------------------------------
// small utility kernels
// ---------------------------------------------------------------------------
__global__ void fill_kernel(float* p, float v, int n) {
    for (int i = blockIdx.x * blockDim.x + threadIdx.x; i < n; i += gridDim.x * blockDim.x)
        p[i] = v;
}

// fused 8-way f32 -> bf16 weight conversion (all sizes % 1024 == 0)
struct Cvt8 {
    const float* s[8];
    bf16* d[8];
    int boff[9];
};
__global__ __launch_bounds__(256) void cvt8_kernel(Cvt8 c) {
    int blk = blockIdx.x;
    int seg = 0;
#pragma unroll
    for (int k = 0; k < 7; ++k)
        if (blk >= c.boff[k + 1]) seg = k + 1;
    const int local = blk - c.boff[seg];
    const int i = local * 1024 + threadIdx.x * 4;
    const float4 v = *(const float4*)(c.s[seg] + i);
    bf16x4 o;
    o[0] = (bf16)v.x; o[1] = (bf16)v.y; o[2] = (bf16)v.z; o[3] = (bf16)v.w;
    *(bf16x4*)(c.d[seg] + i) = o;
}

// ---------------------------------------------------------------------------
// complex magnitude layernorm. ILV=true: xa is interleaved float2 [row][768][2]
// ---------------------------------------------------------------------------
template <bool ILV>
__global__ __launch_bounds__(256) void cln_kernel(
    const float* __restrict__ xa, const float* __restrict__ xb,
    const float* __restrict__ gamma, const float* __restrict__ beta,
    bf16* __restrict__ nr, bf16* __restrict__ ni) {
    __shared__ float red[4];
    const int t = threadIdx.x;
    const size_t base = (size_t)blockIdx.x * 768;

    float r[3], im[3], mg[3];
#pragma unroll
    for (int j = 0; j < 3; ++j) {
        const int f = t + j * 256;
        if (ILV) {
            const float2 v = ((const float2*)xa)[base + f];
            r[j] = v.x;
            im[j] = v.y;
        } else {
            r[j] = xa[base + f];
            im[j] = xb[base + f];
        }
        mg[j] = __builtin_amdgcn_sqrtf(r[j] * r[j] + im[j] * im[j] + 1e-6f);
    }
    float s = mg[0] + mg[1] + mg[2];
#pragma unroll
    for (int m = 32; m >= 1; m >>= 1) s += __shfl_xor(s, m);
    if ((t & 63) == 0) red[t >> 6] = s;
    __syncthreads();
    const float mean = (red[0] + red[1] + red[2] + red[3]) * (1.0f / 768.0f);
    __syncthreads();

    float v2 = 0.0f;
#pragma unroll
    for (int j = 0; j < 3; ++j) {
        const float d = mg[j] - mean;
        v2 += d * d;
    }
#pragma unroll
    for (int m = 32; m >= 1; m >>= 1) v2 += __shfl_xor(v2, m);
    if ((t & 63) == 0) red[t >> 6] = v2;
    __syncthreads();
    const float var = (red[0] + red[1] + red[2] + red[3]) * (1.0f / 768.0f);
    const float rstd = rsqrtf(var + 1e-6f);

#pragma unroll
    for (int j = 0; j < 3; ++j) {
        const int f = t + j * 256;
        const float sc = (mg[j] - mean) * rstd / (mg[j] + 1e-6f);
        nr[base + f] = (bf16)(gamma[2 * f] * (r[j] * sc) + beta[2 * f]);
        ni[base + f] = (bf16)(gamma[2 * f + 1] * (im[j] * sc) + beta[2 * f + 1]);
    }
}

// ---------------------------------------------------------------------------
// complex GEMM (NT) with global_load_lds staging + XCD-aware block swizzle
// ---------------------------------------------------------------------------
template <int MODE>
__global__ __launch_bounds__(256, 2) void cgemm_kernel(
    const bf16* __restrict__ Ar, const bf16* __restrict__ Ai,
    const bf16* __restrict__ Wr, const bf16* __restrict__ Wi,
    const float* __restrict__ br, const float* __restrict__ bi,
    const float* __restrict__ resr, const float* __restrict__ resi,
    float* __restrict__ outFr, float* __restrict__ outFi,
    bf16* __restrict__ outBr, bf16* __restrict__ outBi,
    int N, int K) {
    __shared__ bf16 sAr[128][32];
    __shared__ bf16 sAi[128][32];
    __shared__ bf16 sBr[128][32];
    __shared__ bf16 sBi[128][32];

    const int tid = threadIdx.x;
    const int wave = tid >> 6, lane = tid & 63;
    const int lg = lane >> 4, lr = lane & 15;

    const int nwgx = gridDim.x;
    int wg = blockIdx.y * nwgx + blockIdx.x;
    const int cpx = (nwgx * gridDim.y) >> 3;
    wg = (wg & 7) * cpx + (wg >> 3);
    const int row0 = (wg % nwgx) * 128, col0 = (wg / nwgx) * 128;

    const int wm = (wave >> 1) * 64, wn = (wave & 1) * 64;
    const int srow = lane >> 2;
    const int sc8 = (lane & 3) * 8;

    f32x4 accr[4][4], acci[4][4];
#pragma unroll
    for (int a = 0; a < 4; ++a)
#pragma unroll
        for (int b2 = 0; b2 < 4; ++b2) {
            accr[a][b2] = zero4();
            acci[a][b2] = zero4();
        }

    for (int kt = 0; kt < K; kt += 32) {
        __syncthreads();
#pragma unroll
        for (int s = 0; s < 2; ++s) {
            const int seg = wave * 2 + s;
            const int row = seg * 16 + srow;
            const size_t ga = (size_t)(row0 + row) * K + kt + sc8;
            const size_t gb = (size_t)(col0 + row) * K + kt + sc8;
            gl_lds16(Ar + ga, &sAr[seg * 16][0]);
            gl_lds16(Ai + ga, &sAi[seg * 16][0]);
            gl_lds16(Wr + gb, &sBr[seg * 16][0]);
            gl_lds16(Wi + gb, &sBi[seg * 16][0]);
        }
        __syncthreads();

        bf16x8 ar[4], ai[4], an[4];
#pragma unroll
        for (int mt = 0; mt < 4; ++mt) {
            ar[mt] = *(const bf16x8*)(&sAr[wm + mt * 16 + lr][lg * 8]);
            ai[mt] = *(const bf16x8*)(&sAi[wm + mt * 16 + lr][lg * 8]);
            an[mt] = bneg8(ai[mt]);
        }
#pragma unroll
        for (int nt = 0; nt < 4; ++nt) {
            const bf16x8 br8 = *(const bf16x8*)(&sBr[wn + nt * 16 + lr][lg * 8]);
            const bf16x8 bi8 = *(const bf16x8*)(&sBi[wn + nt * 16 + lr][lg * 8]);
#pragma unroll
            for (int mt = 0; mt < 4; ++mt) {
                accr[mt][nt] = MFMA16(ar[mt], br8, accr[mt][nt]);
                accr[mt][nt] = MFMA16(an[mt], bi8, accr[mt][nt]);
                acci[mt][nt] = MFMA16(ar[mt], bi8, acci[mt][nt]);
                acci[mt][nt] = MFMA16(ai[mt], br8, acci[mt][nt]);
            }
        }
    }

#pragma unroll
    for (int nt = 0; nt < 4; ++nt) {
        const int col = col0 + wn + nt * 16 + lr;
        const float bre = br[col], bie = bi[col];
#pragma unroll
        for (int mt = 0; mt < 4; ++mt) {
#pragma unroll
            for (int j = 0; j < 4; ++j) {
                const int row = row0 + wm + mt * 16 + lg * 4 + j;
                float vr = accr[mt][nt][j] + bre;
                float vi = acci[mt][nt][j] + bie;
                const size_t o = (size_t)row * N + col;
                if (MODE == 0) {
                    outBr[o] = (bf16)vr;
                    outBi[o] = (bf16)vi;
                } else if (MODE == 1) {
                    const float2 rv = ((const float2*)resr)[(size_t)row * 768 + col];
                    outFr[o] = rv.x + vr;
                    outFi[o] = rv.y + vi;
                } else if (MODE == 2) {
                    vr = 0.5f * vr * (1.0f + erff(vr * 0.70710678118654752f));
                    vi = 0.5f * vi * (1.0f + erff(vi * 0.70710678118654752f));
                    outBr[o] = (bf16)vr;
                    outBi[o] = (bf16)vi;
                } else {
                    const size_t ro = (size_t)row * 768 + col;
                    outFr[(size_t)row * 1536 + 2 * col]     = resr[ro] + vr;
                    outFr[(size_t)row * 1536 + 2 * col + 1] = resi[ro] + vi;
                }
            }
        }
    }
}

// ---------------------------------------------------------------------------
// transpose V slice of qkv into [B*nH][64 d][2048 n] bf16 planes
// ---------------------------------------------------------------------------
__global__ __launch_bounds__(256) void vtrans_kernel(
    const bf16* __restrict__ qkvr, const bf16* __restrict__ qkvi,
    bf16* __restrict__ vtr, bf16* __restrict__ vti) {
    __shared__ bf16 sr[64][65];
    __shared__ bf16 si[64][65];
    const int t = threadIdx.x;
    const int nb = blockIdx.x, h = blockIdx.y, b = blockIdx.z;
    const size_t ld = 2304;
    const bf16* srcr = qkvr + (size_t)(b * 2048 + nb * 64) * ld + 1536 + h * 64;
    const bf16* srci = qkvi + (size_t)(b * 2048 + nb * 64) * ld + 1536 + h * 64;
#pragma unroll
    for (int j = 0; j < 16; ++j) {
        const int idx = t + 256 * j;
        const int n = idx >> 6, d = idx & 63;
        sr[n][d] = srcr[(size_t)n * ld + d];
        si[n][d] = srci[(size_t)n * ld + d];
    }
    __syncthreads();
    bf16* dstr = vtr + (size_t)(b * 12 + h) * 64 * 2048 + nb * 64;
    bf16* dsti = vti + (size_t)(b * 12 + h) * 64 * 2048 + nb * 64;
#pragma unroll
    for (int j = 0; j < 16; ++j) {
        const int idx = t + 256 * j;
        const int d = idx >> 6, n = idx & 63;
        dstr[(size_t)d * 2048 + n] = sr[n][d];
        dsti[(size_t)d * 2048 + n] = si[n][d];
    }
}

// ---------------------------------------------------------------------------
// fused complex flash attention v4:
// 4 waves x 32 q-rows (block = 128 q), 64-key tiles,
// double-buffered K/V via global_load_lds (source-side XOR swizzle),
// one barrier per iteration.
// ---------------------------------------------------------------------------
__global__ __launch_bounds__(256, 2) void cattn_kernel(
    const bf16* __restrict__ qkvr, const bf16* __restrict__ qkvi,
    const bf16* __restrict__ vtr, const bf16* __restrict__ vti,
    bf16* __restrict__ aor, bf16* __restrict__ aoi) {
    __shared__ __align__(16) bf16 sK[2][2][64][64];  // [buf][plane][key][d]
    __shared__ __align__(16) bf16 sV[2][2][64][64];  // [buf][plane][d][key]
    __shared__ __align__(16) bf16 sP[4][16][72];     // per-wave P

    const int tid = threadIdx.x;
    const int w = tid >> 6, lane = tid & 63;
    const int lg = lane >> 4, lr = lane & 15;
    const int qb = blockIdx.x, h = blockIdx.y, b = blockIdx.z;
    const int ld = 2304;
    const int kx = lr & 7;

    // staging lane constants: row within 8-row segment + swizzled chunk
    const int srow = lane >> 3;                    // 0..7
    const int scg8 = ((lane & 7) ^ srow) * 8;      // pre-swizzled source chunk

    const bf16* kbase0 = qkvr + (size_t)b * 2048 * ld + 768 + h * 64;
    const bf16* kbase1 = qkvi + (size_t)b * 2048 * ld + 768 + h * 64;
    const bf16* vbase0 = vtr + (size_t)(b * 12 + h) * 64 * 2048;
    const bf16* vbase1 = vti + (size_t)(b * 12 + h) * 64 * 2048;

    auto stage = [&](int buf, int kt) {
#pragma unroll
        for (int s = 0; s < 2; ++s) {
            const int seg = w * 2 + s;       // 0..7
            const int row = seg * 8 + srow;  // 0..63
            gl_lds16(kbase0 + (size_t)(kt * 64 + row) * ld + scg8, &sK[buf][0][seg * 8][0]);
            gl_lds16(kbase1 + (size_t)(kt * 64 + row) * ld + scg8, &sK[buf][1][seg * 8][0]);
            gl_lds16(vbase0 + (size_t)row * 2048 + kt * 64 + scg8, &sV[buf][0][seg * 8][0]);
            gl_lds16(vbase1 + (size_t)row * 2048 + kt * 64 + scg8, &sV[buf][1][seg * 8][0]);
        }
    };

    stage(0, 0);

    // Q fragments: 2 q-tiles of 16 rows per wave
    bf16x8 aqr[2][2], aqi[2][2];
#pragma unroll
    for (int qt = 0; qt < 2; ++qt) {
        const size_t qoff =
            (size_t)(b * 2048 + qb * 128 + w * 32 + qt * 16 + lr) * ld + h * 64;
#pragma unroll
        for (int ks = 0; ks < 2; ++ks) {
            aqr[qt][ks] = *(const bf16x8*)(qkvr + qoff + ks * 32 + lg * 8);
            aqi[qt][ks] = *(const bf16x8*)(qkvi + qoff + ks * 32 + lg * 8);
        }
    }

    f32x4 our[2][4], oui[2][4];
#pragma unroll
    for (int qt = 0; qt < 2; ++qt)
#pragma unroll
        for (int d = 0; d < 4; ++d) {
            our[qt][d] = zero4();
            oui[qt][d] = zero4();
        }
    float mrun[2] = {-1e30f, -1e30f}, lrun[2] = {0.0f, 0.0f};

    __syncthreads();  // buf0 staged (barrier drains vmcnt)

    for (int kt = 0; kt < 32; ++kt) {
        const int cur = kt & 1;
        if (kt < 31) stage(cur ^ 1, kt + 1);  // fire-and-forget prefetch

        // ---- QK^T with per-t magnitude ----
        float pq[2][16];
        float tmax[2] = {-1e30f, -1e30f};
#pragma unroll
        for (int t = 0; t < 4; ++t) {
            f32x4 str[2], sti[2];
#pragma unroll
            for (int qt = 0; qt < 2; ++qt) {
                str[qt] = zero4();
                sti[qt] = zero4();
            }
#pragma unroll
            for (int ks = 0; ks < 2; ++ks) {
                const int ch = (((ks << 2) | lg) ^ kx) << 3;
                const bf16x8 kr8 = *(const bf16x8*)(&sK[cur][0][t * 16 + lr][ch]);
                const bf16x8 ki8 = *(const bf16x8*)(&sK[cur][1][t * 16 + lr][ch]);
                const bf16x8 kn8 = bneg8(kr8);
#pragma unroll
                for (int qt = 0; qt < 2; ++qt) {
                    str[qt] = MFMA16(kr8, aqr[qt][ks], str[qt]);
                    str[qt] = MFMA16(ki8, aqi[qt][ks], str[qt]);
                    sti[qt] = MFMA16(ki8, aqr[qt][ks], sti[qt]);
                    sti[qt] = MFMA16(kn8, aqi[qt][ks], sti[qt]);
                }
            }
#pragma unroll
            for (int qt = 0; qt < 2; ++qt)
#pragma unroll
                for (int j = 0; j < 4; ++j) {
                    const float sr = str[qt][j], si = sti[qt][j];
                    const float m =
                        __builtin_amdgcn_sqrtf(sr * sr + si * si + 1e-8f) * 0.125f;
                    pq[qt][t * 4 + j] = m;
                    tmax[qt] = fmaxf(tmax[qt], m);
                }
        }

        // ---- softmax per q-tile, P -> LDS -> PV A-fragments ----
        bf16x8 pf[2][2];
#pragma unroll
        for (int qt = 0; qt < 2; ++qt) {
            float tm = tmax[qt];
            tm = fmaxf(tm, __shfl_xor(tm, 16));
            tm = fmaxf(tm, __shfl_xor(tm, 32));

            if (!__all(tm <= mrun[qt])) {
                const float mnew = fmaxf(mrun[qt], tm);
                const float corr = __builtin_amdgcn_exp2f((mrun[qt] - mnew) * LOG2E);
                float cj[4];
#pragma unroll
                for (int j = 0; j < 4; ++j) cj[j] = __shfl(corr, lg * 4 + j);
#pragma unroll
                for (int d = 0; d < 4; ++d)
#pragma unroll
                    for (int j = 0; j < 4; ++j) {
                        our[qt][d][j] *= cj[j];
                        oui[qt][d][j] *= cj[j];
                    }
                lrun[qt] *= corr;
                mrun[qt] = mnew;
            }

            float ls = 0.0f;
#pragma unroll
            for (int i = 0; i < 16; ++i) {
                pq[qt][i] = __builtin_amdgcn_exp2f((pq[qt][i] - mrun[qt]) * LOG2E);
                ls += pq[qt][i];
            }
            ls += __shfl_xor(ls, 16);
            ls += __shfl_xor(ls, 32);
            lrun[qt] += ls;

#pragma unroll
            for (int t = 0; t < 4; ++t) {
                bf16x4 pk;
#pragma unroll
                for (int j = 0; j < 4; ++j) pk[j] = (bf16)pq[qt][t * 4 + j];
                *(bf16x4*)(&sP[w][lr][t * 16 + lg * 4]) = pk;
            }
            pf[qt][0] = *(const bf16x8*)(&sP[w][lr][lg * 8]);
            pf[qt][1] = *(const bf16x8*)(&sP[w][lr][32 + lg * 8]);
        }

        // ---- PV: V fragments shared across both q-tiles ----
#pragma unroll
        for (int d = 0; d < 4; ++d) {
#pragma unroll
            for (int ks2 = 0; ks2 < 2; ++ks2) {
                const int ch = (((ks2 << 2) | lg) ^ kx) << 3;
                const bf16x8 vr8 = *(const bf16x8*)(&sV[cur][0][d * 16 + lr][ch]);
                const bf16x8 vi8 = *(const bf16x8*)(&sV[cur][1][d * 16 + lr][ch]);
#pragma unroll
                for (int qt = 0; qt < 2; ++qt) {
                    our[qt][d] = MFMA16(pf[qt][ks2], vr8, our[qt][d]);
                    oui[qt][d] = MFMA16(pf[qt][ks2], vi8, oui[qt][d]);
                }
            }
        }
        __syncthreads();  // drains staging vmcnt + all LDS reads before overwrite
    }

#pragma unroll
    for (int qt = 0; qt < 2; ++qt) {
        float linv[4];
#pragma unroll
        for (int j = 0; j < 4; ++j) {
            const float lj = __shfl(lrun[qt], lg * 4 + j);
            linv[j] = __builtin_amdgcn_rcpf(lj);
        }
#pragma unroll
        for (int d = 0; d < 4; ++d)
#pragma unroll
            for (int j = 0; j < 4; ++j) {
                const int row = b * 2048 + qb * 128 + w * 32 + qt * 16 + lg * 4 + j;
                const int col = h * 64 + d * 16 + lr;
                aor[(size_t)row * 768 + col] = (bf16)(our[qt][d][j] * linv[j]);
                aoi[(size_t)row * 768 + col] = (bf16)(oui[qt][d][j] * linv[j]);
            }
    }
}

// ---------------------------------------------------------------------------
// host launch
// ---------------------------------------------------------------------------
extern "C" void kernel_launch(void* const* d_in, const int* in_sizes, int n_in,
                              void* d_out, int out_size, void* d_ws, size_t ws_size,
                              hipStream_t stream) {
    const float* x      = (const float*)d_in[0];
    const float* n1g    = (const float*)d_in[1];
    const float* n1b    = (const float*)d_in[2];
    const float* qkvwr  = (const float*)d_in[3];
    const float* qkvwi  = (const float*)d_in[4];
    const float* qkvbr  = (const float*)d_in[5];
    const float* qkvbi  = (const float*)d_in[6];
    const float* projwr = (const float*)d_in[7];
    const float* projwi = (const float*)d_in[8];
    const float* projbr = (const float*)d_in[9];
    const float* projbi = (const float*)d_in[10];
    const float* n2g    = (const float*)d_in[11];
    const float* n2b    = (const float*)d_in[12];
    const float* fc1wr  = (const float*)d_in[13];
    const float* fc1wi  = (const float*)d_in[14];
    const float* fc1br  = (const float*)d_in[15];
    const float* fc1bi  = (const float*)d_in[16];
    const float* fc2wr  = (const float*)d_in[17];
    const float* fc2wi  = (const float*)d_in[18];
    const float* fc2br  = (const float*)d_in[19];
    const float* fc2bi  = (const float*)d_in[20];

    const int M = 4096, E = 768, E3 = 2304, HH = 1536;

    char* base = (char*)d_ws;
    size_t off = 0;
    auto alloc = [&](size_t bytes) -> void* {
        void* p = base + off;
        off += (bytes + 255) & ~(size_t)255;
        return p;
    };
    float* xr2 = (float*)alloc((size_t)M * E * 4);
    float* xi2 = (float*)alloc((size_t)M * E * 4);
    bf16* nr   = (bf16*)alloc((size_t)M * E * 2);
    bf16* ni   = (bf16*)alloc((size_t)M * E * 2);
    bf16* wqr  = (bf16*)alloc((size_t)E3 * E * 2);
    bf16* wqi  = (bf16*)alloc((size_t)E3 * E * 2);
    bf16* wpr  = (bf16*)alloc((size_t)E * E * 2);
    bf16* wpi  = (bf16*)alloc((size_t)E * E * 2);
    bf16* w1r  = (bf16*)alloc((size_t)HH * E * 2);
    bf16* w1i  = (bf16*)alloc((size_t)HH * E * 2);
    bf16* w2r  = (bf16*)alloc((size_t)E * HH * 2);
    bf16* w2i  = (bf16*)alloc((size_t)E * HH * 2);
    bf16* qkr  = (bf16*)alloc((size_t)M * E3 * 2);
    bf16* qki  = (bf16*)alloc((size_t)M * E3 * 2);
    bf16* vtr  = (bf16*)alloc((size_t)24 * 64 * 2048 * 2);
    bf16* vti  = (bf16*)alloc((size_t)24 * 64 * 2048 * 2);
    bf16* aor  = (bf16*)alloc((size_t)M * E * 2);
    bf16* aoi  = (bf16*)alloc((size_t)M * E * 2);
    bf16* hr   = (bf16*)alloc((size_t)M * HH * 2);
    bf16* hi   = (bf16*)alloc((size_t)M * HH * 2);

    if (off > ws_size) {
        fill_kernel<<<1024, 256, 0, stream>>>((float*)d_out, 1.0e9f, out_size);
        return;
    }

    // fused weight conversion
    Cvt8 c;
    c.s[0] = qkvwr; c.d[0] = wqr;
    c.s[1] = qkvwi; c.d[1] = wqi;
    c.s[2] = projwr; c.d[2] = wpr;
    c.s[3] = projwi; c.d[3] = wpi;
    c.s[4] = fc1wr; c.d[4] = w1r;
    c.s[5] = fc1wi; c.d[5] = w1i;
    c.s[6] = fc2wr; c.d[6] = w2r;
    c.s[7] = fc2wi; c.d[7] = w2i;
    const int nseg[8] = {E3 * E, E3 * E, E * E, E * E, HH * E, HH * E, E * HH, E * HH};
    int cum = 0;
    for (int k = 0; k < 8; ++k) {
        c.boff[k] = cum;
        cum += nseg[k] / 1024;
    }
    c.boff[8] = cum;
    cvt8_kernel<<<cum, 256, 0, stream>>>(c);

    // LN1 (reads interleaved x directly)
    cln_kernel<true><<<M, 256, 0, stream>>>(x, nullptr, n1g, n1b, nr, ni);
    // QKV
    cgemm_kernel<0><<<dim3(32, 18), 256, 0, stream>>>(nr, ni, wqr, wqi, qkvbr, qkvbi,
                                                      nullptr, nullptr, nullptr, nullptr,
                                                      qkr, qki, E3, E);
    // V transpose
    vtrans_kernel<<<dim3(32, 12, 2), 256, 0, stream>>>(qkr, qki, vtr, vti);
    // attention (128 q-rows per block)
    cattn_kernel<<<dim3(16, 12, 2), 256, 0, stream>>>(qkr, qki, vtr, vti, aor, aoi);
    // proj + interleaved-x residual -> f32 planes
    cgemm_kernel<1><<<dim3(32, 6), 256, 0, stream>>>(aor, aoi, wpr, wpi, projbr, projbi,
                                                     x, nullptr, xr2, xi2, nullptr, nullptr,
                                                     E, E);
    // LN2
    cln_kernel<false><<<M, 256, 0, stream>>>(xr2, xi2, n2g, n2b, nr, ni);
    // FC1 + gelu
    cgemm_kernel<2><<<dim3(32, 12), 256, 0, stream>>>(nr, ni, w1r, w1i, fc1br, fc1bi,
                                                      nullptr, nullptr, nullptr, nullptr,
                                                      hr, hi, HH, E);
    // FC2 + residual -> interleaved d_out
    cgemm_kernel<3><<<dim3(32, 6), 256, 0, stream>>>(hr, hi, w2r, w2i, fc2br, fc2bi,
                                                     xr2, xi2, (float*)d_out, nullptr,
                                                     nullptr, nullptr, E, HH);
}

// Round 5
// 409.325 us; speedup vs baseline: 1.2664x; 1.0141x over previous
//
#include <hip/hip_runtime.h>
#include <cmath>

typedef __bf16 bf16;
typedef __bf16 bf16x8 __attribute__((ext_vector_type(8)));
typedef __bf16 bf16x4 __attribute__((ext_vector_type(4)));
typedef float  f32x4  __attribute__((ext_vector_type(4)));
typedef unsigned int u32x4 __attribute__((ext_vector_type(4)));

#define MFMA16(a, b, c) __builtin_amdgcn_mfma_f32_16x16x32_bf16((a), (b), (c), 0, 0, 0)
#define LOG2E 1.44269504088896f

static __device__ __forceinline__ void gl_lds16(const void* g, void* l) {
    __builtin_amdgcn_global_load_lds((const __attribute__((address_space(1))) void*)g,
                                     (__attribute__((address_space(3))) void*)l, 16, 0, 0);
}

static __device__ __forceinline__ bf16x8 bneg8(bf16x8 x) {
    u32x4 u = __builtin_bit_cast(u32x4, x);
    u = u ^ 0x80008000u;
    return __builtin_bit_cast(bf16x8, u);
}

static __device__ __forceinline__ f32x4 zero4() {
    return f32x4{0.0f, 0.0f, 0.0f, 0.0f};
}

// ---------------------------------------------------------------------------
// small utility kernels
// ---------------------------------------------------------------------------
__global__ void fill_kernel(float* p, float v, int n) {
    for (int i = blockIdx.x * blockDim.x + threadIdx.x; i < n; i += gridDim.x * blockDim.x)
        p[i] = v;
}

// fused 8-way f32 -> bf16 weight conversion (all sizes % 1024 == 0)
struct Cvt8 {
    const float* s[8];
    bf16* d[8];
    int boff[9];
};
__global__ __launch_bounds__(256) void cvt8_kernel(Cvt8 c) {
    int blk = blockIdx.x;
    int seg = 0;
#pragma unroll
    for (int k = 0; k < 7; ++k)
        if (blk >= c.boff[k + 1]) seg = k + 1;
    const int local = blk - c.boff[seg];
    const int i = local * 1024 + threadIdx.x * 4;
    const float4 v = *(const float4*)(c.s[seg] + i);
    bf16x4 o;
    o[0] = (bf16)v.x; o[1] = (bf16)v.y; o[2] = (bf16)v.z; o[3] = (bf16)v.w;
    *(bf16x4*)(c.d[seg] + i) = o;
}

// ---------------------------------------------------------------------------
// complex magnitude layernorm. ILV=true: xa is interleaved float2 [row][768][2]
// ---------------------------------------------------------------------------
template <bool ILV>
__global__ __launch_bounds__(256) void cln_kernel(
    const float* __restrict__ xa, const float* __restrict__ xb,
    const float* __restrict__ gamma, const float* __restrict__ beta,
    bf16* __restrict__ nr, bf16* __restrict__ ni) {
    __shared__ float red[4];
    const int t = threadIdx.x;
    const size_t base = (size_t)blockIdx.x * 768;

    float r[3], im[3], mg[3];
#pragma unroll
    for (int j = 0; j < 3; ++j) {
        const int f = t + j * 256;
        if (ILV) {
            const float2 v = ((const float2*)xa)[base + f];
            r[j] = v.x;
            im[j] = v.y;
        } else {
            r[j] = xa[base + f];
            im[j] = xb[base + f];
        }
        mg[j] = __builtin_amdgcn_sqrtf(r[j] * r[j] + im[j] * im[j] + 1e-6f);
    }
    float s = mg[0] + mg[1] + mg[2];
#pragma unroll
    for (int m = 32; m >= 1; m >>= 1) s += __shfl_xor(s, m);
    if ((t & 63) == 0) red[t >> 6] = s;
    __syncthreads();
    const float mean = (red[0] + red[1] + red[2] + red[3]) * (1.0f / 768.0f);
    __syncthreads();

    float v2 = 0.0f;
#pragma unroll
    for (int j = 0; j < 3; ++j) {
        const float d = mg[j] - mean;
        v2 += d * d;
    }
#pragma unroll
    for (int m = 32; m >= 1; m >>= 1) v2 += __shfl_xor(v2, m);
    if ((t & 63) == 0) red[t >> 6] = v2;
    __syncthreads();
    const float var = (red[0] + red[1] + red[2] + red[3]) * (1.0f / 768.0f);
    const float rstd = rsqrtf(var + 1e-6f);

#pragma unroll
    for (int j = 0; j < 3; ++j) {
        const int f = t + j * 256;
        const float sc = (mg[j] - mean) * rstd / (mg[j] + 1e-6f);
        nr[base + f] = (bf16)(gamma[2 * f] * (r[j] * sc) + beta[2 * f]);
        ni[base + f] = (bf16)(gamma[2 * f + 1] * (im[j] * sc) + beta[2 * f + 1]);
    }
}

// ---------------------------------------------------------------------------
// complex GEMM (NT) with global_load_lds staging + XCD-aware block swizzle
// ---------------------------------------------------------------------------
template <int MODE>
__global__ __launch_bounds__(256, 2) void cgemm_kernel(
    const bf16* __restrict__ Ar, const bf16* __restrict__ Ai,
    const bf16* __restrict__ Wr, const bf16* __restrict__ Wi,
    const float* __restrict__ br, const float* __restrict__ bi,
    const float* __restrict__ resr, const float* __restrict__ resi,
    float* __restrict__ outFr, float* __restrict__ outFi,
    bf16* __restrict__ outBr, bf16* __restrict__ outBi,
    int N, int K) {
    __shared__ bf16 sAr[128][32];
    __shared__ bf16 sAi[128][32];
    __shared__ bf16 sBr[128][32];
    __shared__ bf16 sBi[128][32];

    const int tid = threadIdx.x;
    const int wave = tid >> 6, lane = tid & 63;
    const int lg = lane >> 4, lr = lane & 15;

    const int nwgx = gridDim.x;
    int wg = blockIdx.y * nwgx + blockIdx.x;
    const int cpx = (nwgx * gridDim.y) >> 3;
    wg = (wg & 7) * cpx + (wg >> 3);
    const int row0 = (wg % nwgx) * 128, col0 = (wg / nwgx) * 128;

    const int wm = (wave >> 1) * 64, wn = (wave & 1) * 64;
    const int srow = lane >> 2;
    const int sc8 = (lane & 3) * 8;

    f32x4 accr[4][4], acci[4][4];
#pragma unroll
    for (int a = 0; a < 4; ++a)
#pragma unroll
        for (int b2 = 0; b2 < 4; ++b2) {
            accr[a][b2] = zero4();
            acci[a][b2] = zero4();
        }

    for (int kt = 0; kt < K; kt += 32) {
        __syncthreads();
#pragma unroll
        for (int s = 0; s < 2; ++s) {
            const int seg = wave * 2 + s;
            const int row = seg * 16 + srow;
            const size_t ga = (size_t)(row0 + row) * K + kt + sc8;
            const size_t gb = (size_t)(col0 + row) * K + kt + sc8;
            gl_lds16(Ar + ga, &sAr[seg * 16][0]);
            gl_lds16(Ai + ga, &sAi[seg * 16][0]);
            gl_lds16(Wr + gb, &sBr[seg * 16][0]);
            gl_lds16(Wi + gb, &sBi[seg * 16][0]);
        }
        __syncthreads();

        bf16x8 ar[4], ai[4], an[4];
#pragma unroll
        for (int mt = 0; mt < 4; ++mt) {
            ar[mt] = *(const bf16x8*)(&sAr[wm + mt * 16 + lr][lg * 8]);
            ai[mt] = *(const bf16x8*)(&sAi[wm + mt * 16 + lr][lg * 8]);
            an[mt] = bneg8(ai[mt]);
        }
#pragma unroll
        for (int nt = 0; nt < 4; ++nt) {
            const bf16x8 br8 = *(const bf16x8*)(&sBr[wn + nt * 16 + lr][lg * 8]);
            const bf16x8 bi8 = *(const bf16x8*)(&sBi[wn + nt * 16 + lr][lg * 8]);
#pragma unroll
            for (int mt = 0; mt < 4; ++mt) {
                accr[mt][nt] = MFMA16(ar[mt], br8, accr[mt][nt]);
                accr[mt][nt] = MFMA16(an[mt], bi8, accr[mt][nt]);
                acci[mt][nt] = MFMA16(ar[mt], bi8, acci[mt][nt]);
                acci[mt][nt] = MFMA16(ai[mt], br8, acci[mt][nt]);
            }
        }
    }

#pragma unroll
    for (int nt = 0; nt < 4; ++nt) {
        const int col = col0 + wn + nt * 16 + lr;
        const float bre = br[col], bie = bi[col];
#pragma unroll
        for (int mt = 0; mt < 4; ++mt) {
#pragma unroll
            for (int j = 0; j < 4; ++j) {
                const int row = row0 + wm + mt * 16 + lg * 4 + j;
                float vr = accr[mt][nt][j] + bre;
                float vi = acci[mt][nt][j] + bie;
                const size_t o = (size_t)row * N + col;
                if (MODE == 0) {
                    outBr[o] = (bf16)vr;
                    outBi[o] = (bf16)vi;
                } else if (MODE == 1) {
                    const float2 rv = ((const float2*)resr)[(size_t)row * 768 + col];
                    outFr[o] = rv.x + vr;
                    outFi[o] = rv.y + vi;
                } else if (MODE == 2) {
                    vr = 0.5f * vr * (1.0f + erff(vr * 0.70710678118654752f));
                    vi = 0.5f * vi * (1.0f + erff(vi * 0.70710678118654752f));
                    outBr[o] = (bf16)vr;
                    outBi[o] = (bf16)vi;
                } else {
                    const size_t ro = (size_t)row * 768 + col;
                    outFr[(size_t)row * 1536 + 2 * col]     = resr[ro] + vr;
                    outFr[(size_t)row * 1536 + 2 * col + 1] = resi[ro] + vi;
                }
            }
        }
    }
}

// ---------------------------------------------------------------------------
// transpose V slice of qkv into [B*nH][64 d][2048 n] bf16 planes
// ---------------------------------------------------------------------------
__global__ __launch_bounds__(256) void vtrans_kernel(
    const bf16* __restrict__ qkvr, const bf16* __restrict__ qkvi,
    bf16* __restrict__ vtr, bf16* __restrict__ vti) {
    __shared__ bf16 sr[64][65];
    __shared__ bf16 si[64][65];
    const int t = threadIdx.x;
    const int nb = blockIdx.x, h = blockIdx.y, b = blockIdx.z;
    const size_t ld = 2304;
    const bf16* srcr = qkvr + (size_t)(b * 2048 + nb * 64) * ld + 1536 + h * 64;
    const bf16* srci = qkvi + (size_t)(b * 2048 + nb * 64) * ld + 1536 + h * 64;
#pragma unroll
    for (int j = 0; j < 16; ++j) {
        const int idx = t + 256 * j;
        const int n = idx >> 6, d = idx & 63;
        sr[n][d] = srcr[(size_t)n * ld + d];
        si[n][d] = srci[(size_t)n * ld + d];
    }
    __syncthreads();
    bf16* dstr = vtr + (size_t)(b * 12 + h) * 64 * 2048 + nb * 64;
    bf16* dsti = vti + (size_t)(b * 12 + h) * 64 * 2048 + nb * 64;
#pragma unroll
    for (int j = 0; j < 16; ++j) {
        const int idx = t + 256 * j;
        const int d = idx >> 6, n = idx & 63;
        dstr[(size_t)d * 2048 + n] = sr[n][d];
        dsti[(size_t)d * 2048 + n] = si[n][d];
    }
}

// ---------------------------------------------------------------------------
// fused complex flash attention v5:
// 4 waves x 16 q-rows (block = 64 q), 32-key tiles double-buffered in LDS,
// small LDS footprint (~38 KB) -> 3 blocks/CU, grid 768 = 3x256 exact fill.
// ---------------------------------------------------------------------------
__global__ __launch_bounds__(256, 3) void cattn_kernel(
    const bf16* __restrict__ qkvr, const bf16* __restrict__ qkvi,
    const bf16* __restrict__ vtr, const bf16* __restrict__ vti,
    bf16* __restrict__ aor, bf16* __restrict__ aoi) {
    __shared__ __align__(16) bf16 sK[2][2][32][64];  // [buf][plane][key][d]
    __shared__ __align__(16) bf16 sV[2][2][64][32];  // [buf][plane][d][key]
    __shared__ __align__(16) bf16 sP[4][16][40];     // per-wave P (32 keys, padded)

    const int tid = threadIdx.x;
    const int w = tid >> 6, lane = tid & 63;
    const int lg = lane >> 4, lr = lane & 15;
    const int qb = blockIdx.x, h = blockIdx.y, b = blockIdx.z;
    const int ld = 2304;

    // staging lane constants (inverse-swizzled global chunk, linear LDS dest)
    const int s_krow = lane >> 3;                  // 0..7 row within 8-row K seg
    const int s_kch8 = ((lane & 7) ^ s_krow) * 8;  // K source chunk (elements)
    const int s_vrow = lane >> 2;                  // 0..15 row within 16-row V seg
    const int s_vch8 = ((lane & 3) ^ (s_vrow & 3)) * 8;

    const bf16* kbase0 = qkvr + (size_t)b * 2048 * ld + 768 + h * 64;
    const bf16* kbase1 = qkvi + (size_t)b * 2048 * ld + 768 + h * 64;
    const bf16* vbase0 = vtr + (size_t)(b * 12 + h) * 64 * 2048;
    const bf16* vbase1 = vti + (size_t)(b * 12 + h) * 64 * 2048;

    auto stage = [&](int buf, int kt) {
#pragma unroll
        for (int s = 0; s < 2; ++s) {
            const int seg = s * 4 + w;             // 0..7
            const int pl = seg >> 2, rg = seg & 3; // plane, row-group
            // K: rows rg*8 .. rg*8+7 (8 rows x 128B = 1KB per wave-instr)
            gl_lds16((pl ? kbase1 : kbase0) +
                         (size_t)(kt * 32 + rg * 8 + s_krow) * ld + s_kch8,
                     &sK[buf][pl][rg * 8][0]);
            // V: rows rg*16 .. rg*16+15 (16 rows x 64B = 1KB)
            gl_lds16((pl ? vbase1 : vbase0) +
                         (size_t)(rg * 16 + s_vrow) * 2048 + kt * 32 + s_vch8,
                     &sV[buf][pl][rg * 16][0]);
        }
    };

    stage(0, 0);

    // Q fragments: 16 q-rows per wave
    const size_t qoff = (size_t)(b * 2048 + qb * 64 + w * 16 + lr) * ld + h * 64;
    bf16x8 aqr[2], aqi[2];
#pragma unroll
    for (int ks = 0; ks < 2; ++ks) {
        aqr[ks] = *(const bf16x8*)(qkvr + qoff + ks * 32 + lg * 8);
        aqi[ks] = *(const bf16x8*)(qkvi + qoff + ks * 32 + lg * 8);
    }

    f32x4 our[4], oui[4];
#pragma unroll
    for (int d = 0; d < 4; ++d) {
        our[d] = zero4();
        oui[d] = zero4();
    }
    float mrun = -1e30f, lrun = 0.0f;

    __syncthreads();  // buf0 staged (barrier drains vmcnt)

    for (int kt = 0; kt < 64; ++kt) {
        const int cur = kt & 1;
        if (kt < 63) stage(cur ^ 1, kt + 1);  // fire-and-forget prefetch

        // ---- QK^T: 32 keys x 16 queries ----
        f32x4 str[2], sti[2];
        str[0] = zero4(); str[1] = zero4();
        sti[0] = zero4(); sti[1] = zero4();
#pragma unroll
        for (int t = 0; t < 2; ++t) {
#pragma unroll
            for (int ks = 0; ks < 2; ++ks) {
                const int ch = ((ks << 2) | lg) ^ (lr & 7);
                const bf16x8 kr8 = *(const bf16x8*)(&sK[cur][0][t * 16 + lr][ch * 8]);
                const bf16x8 ki8 = *(const bf16x8*)(&sK[cur][1][t * 16 + lr][ch * 8]);
                const bf16x8 kn8 = bneg8(kr8);
                str[t] = MFMA16(kr8, aqr[ks], str[t]);
                str[t] = MFMA16(ki8, aqi[ks], str[t]);
                sti[t] = MFMA16(ki8, aqr[ks], sti[t]);
                sti[t] = MFMA16(kn8, aqi[ks], sti[t]);
            }
        }

        // ---- magnitude + online softmax (8 scores/lane, q = lr) ----
        float p[8];
        float tmax = -1e30f;
#pragma unroll
        for (int t = 0; t < 2; ++t)
#pragma unroll
            for (int j = 0; j < 4; ++j) {
                const float sr = str[t][j], si = sti[t][j];
                const float m = __builtin_amdgcn_sqrtf(sr * sr + si * si + 1e-8f) * 0.125f;
                p[t * 4 + j] = m;
                tmax = fmaxf(tmax, m);
            }
        tmax = fmaxf(tmax, __shfl_xor(tmax, 16));
        tmax = fmaxf(tmax, __shfl_xor(tmax, 32));

        if (!__all(tmax <= mrun)) {
            const float mnew = fmaxf(mrun, tmax);
            const float corr = __builtin_amdgcn_exp2f((mrun - mnew) * LOG2E);
            float cj[4];
#pragma unroll
            for (int j = 0; j < 4; ++j) cj[j] = __shfl(corr, lg * 4 + j);
#pragma unroll
            for (int d = 0; d < 4; ++d)
#pragma unroll
                for (int j = 0; j < 4; ++j) {
                    our[d][j] *= cj[j];
                    oui[d][j] *= cj[j];
                }
            lrun *= corr;
            mrun = mnew;
        }

        float ls = 0.0f;
#pragma unroll
        for (int i = 0; i < 8; ++i) {
            p[i] = __builtin_amdgcn_exp2f((p[i] - mrun) * LOG2E);
            ls += p[i];
        }
        ls += __shfl_xor(ls, 16);
        ls += __shfl_xor(ls, 32);
        lrun += ls;

        // ---- P -> LDS -> PV A-fragment (within-wave round trip) ----
#pragma unroll
        for (int t = 0; t < 2; ++t) {
            bf16x4 pk;
#pragma unroll
            for (int j = 0; j < 4; ++j) pk[j] = (bf16)p[t * 4 + j];
            *(bf16x4*)(&sP[w][lr][t * 16 + lg * 4]) = pk;
        }
        const bf16x8 pf = *(const bf16x8*)(&sP[w][lr][lg * 8]);

        // ---- PV: 32-key slice = single MFMA k-slot ----
#pragma unroll
        for (int d = 0; d < 4; ++d) {
            const int chv = (lg ^ (lr & 3)) * 8;
            const bf16x8 vr8 = *(const bf16x8*)(&sV[cur][0][d * 16 + lr][chv]);
            const bf16x8 vi8 = *(const bf16x8*)(&sV[cur][1][d * 16 + lr][chv]);
            our[d] = MFMA16(pf, vr8, our[d]);
            oui[d] = MFMA16(pf, vi8, oui[d]);
        }
        __syncthreads();  // drains staging vmcnt + all LDS reads before overwrite
    }

    float linv[4];
#pragma unroll
    for (int j = 0; j < 4; ++j) {
        const float lj = __shfl(lrun, lg * 4 + j);
        linv[j] = __builtin_amdgcn_rcpf(lj);
    }
#pragma unroll
    for (int d = 0; d < 4; ++d)
#pragma unroll
        for (int j = 0; j < 4; ++j) {
            const int row = b * 2048 + qb * 64 + w * 16 + lg * 4 + j;
            const int col = h * 64 + d * 16 + lr;
            aor[(size_t)row * 768 + col] = (bf16)(our[d][j] * linv[j]);
            aoi[(size_t)row * 768 + col] = (bf16)(oui[d][j] * linv[j]);
        }
}

// ---------------------------------------------------------------------------
// host launch
// ---------------------------------------------------------------------------
extern "C" void kernel_launch(void* const* d_in, const int* in_sizes, int n_in,
                              void* d_out, int out_size, void* d_ws, size_t ws_size,
                              hipStream_t stream) {
    const float* x      = (const float*)d_in[0];
    const float* n1g    = (const float*)d_in[1];
    const float* n1b    = (const float*)d_in[2];
    const float* qkvwr  = (const float*)d_in[3];
    const float* qkvwi  = (const float*)d_in[4];
    const float* qkvbr  = (const float*)d_in[5];
    const float* qkvbi  = (const float*)d_in[6];
    const float* projwr = (const float*)d_in[7];
    const float* projwi = (const float*)d_in[8];
    const float* projbr = (const float*)d_in[9];
    const float* projbi = (const float*)d_in[10];
    const float* n2g    = (const float*)d_in[11];
    const float* n2b    = (const float*)d_in[12];
    const float* fc1wr  = (const float*)d_in[13];
    const float* fc1wi  = (const float*)d_in[14];
    const float* fc1br  = (const float*)d_in[15];
    const float* fc1bi  = (const float*)d_in[16];
    const float* fc2wr  = (const float*)d_in[17];
    const float* fc2wi  = (const float*)d_in[18];
    const float* fc2br  = (const float*)d_in[19];
    const float* fc2bi  = (const float*)d_in[20];

    const int M = 4096, E = 768, E3 = 2304, HH = 1536;

    char* base = (char*)d_ws;
    size_t off = 0;
    auto alloc = [&](size_t bytes) -> void* {
        void* p = base + off;
        off += (bytes + 255) & ~(size_t)255;
        return p;
    };
    float* xr2 = (float*)alloc((size_t)M * E * 4);
    float* xi2 = (float*)alloc((size_t)M * E * 4);
    bf16* nr   = (bf16*)alloc((size_t)M * E * 2);
    bf16* ni   = (bf16*)alloc((size_t)M * E * 2);
    bf16* wqr  = (bf16*)alloc((size_t)E3 * E * 2);
    bf16* wqi  = (bf16*)alloc((size_t)E3 * E * 2);
    bf16* wpr  = (bf16*)alloc((size_t)E * E * 2);
    bf16* wpi  = (bf16*)alloc((size_t)E * E * 2);
    bf16* w1r  = (bf16*)alloc((size_t)HH * E * 2);
    bf16* w1i  = (bf16*)alloc((size_t)HH * E * 2);
    bf16* w2r  = (bf16*)alloc((size_t)E * HH * 2);
    bf16* w2i  = (bf16*)alloc((size_t)E * HH * 2);
    bf16* qkr  = (bf16*)alloc((size_t)M * E3 * 2);
    bf16* qki  = (bf16*)alloc((size_t)M * E3 * 2);
    bf16* vtr  = (bf16*)alloc((size_t)24 * 64 * 2048 * 2);
    bf16* vti  = (bf16*)alloc((size_t)24 * 64 * 2048 * 2);
    bf16* aor  = (bf16*)alloc((size_t)M * E * 2);
    bf16* aoi  = (bf16*)alloc((size_t)M * E * 2);
    bf16* hr   = (bf16*)alloc((size_t)M * HH * 2);
    bf16* hi   = (bf16*)alloc((size_t)M * HH * 2);

    if (off > ws_size) {
        fill_kernel<<<1024, 256, 0, stream>>>((float*)d_out, 1.0e9f, out_size);
        return;
    }

    // fused weight conversion
    Cvt8 c;
    c.s[0] = qkvwr; c.d[0] = wqr;
    c.s[1] = qkvwi; c.d[1] = wqi;
    c.s[2] = projwr; c.d[2] = wpr;
    c.s[3] = projwi; c.d[3] = wpi;
    c.s[4] = fc1wr; c.d[4] = w1r;
    c.s[5] = fc1wi; c.d[5] = w1i;
    c.s[6] = fc2wr; c.d[6] = w2r;
    c.s[7] = fc2wi; c.d[7] = w2i;
    const int nseg[8] = {E3 * E, E3 * E, E * E, E * E, HH * E, HH * E, E * HH, E * HH};
    int cum = 0;
    for (int k = 0; k < 8; ++k) {
        c.boff[k] = cum;
        cum += nseg[k] / 1024;
    }
    c.boff[8] = cum;
    cvt8_kernel<<<cum, 256, 0, stream>>>(c);

    // LN1 (reads interleaved x directly)
    cln_kernel<true><<<M, 256, 0, stream>>>(x, nullptr, n1g, n1b, nr, ni);
    // QKV
    cgemm_kernel<0><<<dim3(32, 18), 256, 0, stream>>>(nr, ni, wqr, wqi, qkvbr, qkvbi,
                                                      nullptr, nullptr, nullptr, nullptr,
                                                      qkr, qki, E3, E);
    // V transpose
    vtrans_kernel<<<dim3(32, 12, 2), 256, 0, stream>>>(qkr, qki, vtr, vti);
    // attention (64 q-rows per block; 768 blocks = 3/CU exact)
    cattn_kernel<<<dim3(32, 12, 2), 256, 0, stream>>>(qkr, qki, vtr, vti, aor, aoi);
    // proj + interleaved-x residual -> f32 planes
    cgemm_kernel<1><<<dim3(32, 6), 256, 0, stream>>>(aor, aoi, wpr, wpi, projbr, projbi,
                                                     x, nullptr, xr2, xi2, nullptr, nullptr,
                                                     E, E);
    // LN2
    cln_kernel<false><<<M, 256, 0, stream>>>(xr2, xi2, n2g, n2b, nr, ni);
    // FC1 + gelu
    cgemm_kernel<2><<<dim3(32, 12), 256, 0, stream>>>(nr, ni, w1r, w1i, fc1br, fc1bi,
                                                      nullptr, nullptr, nullptr, nullptr,
                                                      hr, hi, HH, E);
    // FC2 + residual -> interleaved d_out
    cgemm_kernel<3><<<dim3(32, 6), 256, 0, stream>>>(hr, hi, w2r, w2i, fc2br, fc2bi,
                                                     xr2, xi2, (float*)d_out, nullptr,
                                                     nullptr, nullptr, E, HH);
}